// Round 2
// baseline (796.588 us; speedup 1.0000x reference)
//
#include <hip/hip_runtime.h>

typedef unsigned short u16;
typedef __attribute__((ext_vector_type(8))) short short8;
typedef __attribute__((ext_vector_type(4))) float f32x4;

#define B_ 4
#define S_ 8192
#define D_ 1024
#define H_ 4096
#define NTOK (B_*S_)        // 32768
#define MPAD 16384          // padded selected-token count (>= 4*4095)
#define KSEL 4096           // capacity * S

// ---------- helpers ----------
__device__ __forceinline__ u16 f2b(float f) {  // fp32 -> bf16 RNE
    unsigned u = __float_as_uint(f);
    unsigned r = (u + 0x7FFFu + ((u >> 16) & 1u)) >> 16;
    return (u16)r;
}

__device__ __forceinline__ void async_load16(const void* g, void* l) {
    __builtin_amdgcn_global_load_lds(
        (const __attribute__((address_space(1))) void*)g,
        (__attribute__((address_space(3))) void*)l, 16, 0, 0);
}

// ---------- init: zero counter, default indices ----------
__global__ void init_kernel(int* __restrict__ idx, int* __restrict__ cnt) {
    int t = blockIdx.x * 256 + threadIdx.x;
    if (t < MPAD) idx[t] = 0;
    if (t == 0) *cnt = 0;
}

// ---------- router: weights = x.w_r + b_r ; out = x ; xb = bf16(x) ----------
__global__ __launch_bounds__(256)
void router_kernel(const float* __restrict__ x, const float* __restrict__ w_r,
                   const float* __restrict__ b_r, float* __restrict__ out,
                   u16* __restrict__ xb, float* __restrict__ wts) {
    int wv = threadIdx.x >> 6, lane = threadIdx.x & 63;
    long t = (long)blockIdx.x * 4 + wv;           // token id
    const float4* xrow = (const float4*)x + t * 256;
    const float4* wr4  = (const float4*)w_r;
    float4* orow = (float4*)out + t * 256;
    double acc = 0.0;
#pragma unroll
    for (int j = 0; j < 4; ++j) {
        int e = lane + j * 64;
        float4 v = xrow[e];
        float4 w = wr4[e];
        acc += (double)v.x * w.x + (double)v.y * w.y +
               (double)v.z * w.z + (double)v.w * w.w;
        orow[e] = v;
        uint2 hv;
        hv.x = (unsigned)f2b(v.x) | ((unsigned)f2b(v.y) << 16);
        hv.y = (unsigned)f2b(v.z) | ((unsigned)f2b(v.w) << 16);
        *(uint2*)&xb[t * D_ + e * 4] = hv;
    }
#pragma unroll
    for (int off = 32; off > 0; off >>= 1) acc += __shfl_down(acc, off);
    if (lane == 0) wts[t] = (float)(acc + (double)b_r[0]);
}

// ---------- exact k-th largest per batch via 4-pass MSD radix select ----------
__global__ void select_kernel(const float* __restrict__ w, float* __restrict__ thr) {
    int b = blockIdx.x;
    const float* wb = w + b * S_;
    __shared__ int hist[256];
    __shared__ unsigned s_prefix;
    __shared__ int s_rank;
    int tid = threadIdx.x;
    if (tid == 0) { s_prefix = 0u; s_rank = S_ - KSEL; }  // ascending rank 4096
    __syncthreads();
    for (int pass = 0; pass < 4; ++pass) {
        int shift = 24 - 8 * pass;
        hist[tid] = 0;
        __syncthreads();
        unsigned pfx = s_prefix;
        for (int i = tid; i < S_; i += 256) {
            unsigned u = __float_as_uint(wb[i]);
            u = (u & 0x80000000u) ? ~u : (u | 0x80000000u);   // monotonic map
            if (pass == 0 || (u >> (shift + 8)) == pfx)
                atomicAdd(&hist[(u >> shift) & 0xFF], 1);
        }
        __syncthreads();
        if (tid == 0) {
            int r = s_rank;
            unsigned d;
            for (d = 0; d < 256; ++d) { int c = hist[d]; if (r < c) break; r -= c; }
            s_rank = r;
            s_prefix = (s_prefix << 8) | d;
        }
        __syncthreads();
    }
    if (tid == 0) {
        unsigned u = s_prefix;
        unsigned orig = (u & 0x80000000u) ? (u ^ 0x80000000u) : ~u;
        thr[b] = __uint_as_float(orig);
    }
}

// ---------- compact selected token ids ----------
__global__ void compact_kernel(const float* __restrict__ w, const float* __restrict__ thr,
                               int* __restrict__ idx, int* __restrict__ cnt) {
    int t = blockIdx.x * 256 + threadIdx.x;
    int b = t >> 13;
    if (w[t] > thr[b]) {
        int p = atomicAdd(cnt, 1);
        idx[p] = t;
    }
}

// ---------- transpose + cast: W (RxC fp32 row-major) -> Wt (CxR bf16) ----------
__global__ void transpose_kernel(const float* __restrict__ W, u16* __restrict__ Wt,
                                 int R, int C) {
    __shared__ float tile[32][33];
    int c0 = blockIdx.x * 32, r0 = blockIdx.y * 32;
    int tx = threadIdx.x & 31, ty = threadIdx.x >> 5;   // 32 x 8
#pragma unroll
    for (int i = 0; i < 32; i += 8)
        tile[ty + i][tx] = W[(long)(r0 + ty + i) * C + c0 + tx];
    __syncthreads();
#pragma unroll
    for (int i = 0; i < 32; i += 8)
        Wt[(long)(c0 + ty + i) * R + r0 + tx] = f2b(tile[tx][ty + i]);
}

// ---------- GEMM1: hid = gelu(gather(xb) @ W1 + b1), bf16 out ----------
// A: gathered rows of xb (NTOK x D_), B: w1t (H_ x D_ = N x K), C: hid (MPAD x H_)
__global__ __launch_bounds__(256)
void gemm1_kernel(const u16* __restrict__ xb, const u16* __restrict__ w1t,
                  const float* __restrict__ b1, const int* __restrict__ idx,
                  u16* __restrict__ hid) {
    __shared__ u16 As[128 * 64];
    __shared__ u16 Bs[128 * 64];
    const int tid = threadIdx.x;
    const int mtile = blockIdx.y, ntile = blockIdx.x;
    const int wv = tid >> 6, lane = tid & 63;
    const int srow = tid >> 3, scol = (tid & 7) * 8;
    long ab[4], bb[4];
#pragma unroll
    for (int i = 0; i < 4; ++i) {
        int r = mtile * 128 + i * 32 + srow;
        ab[i] = (long)idx[r] * D_ + scol;
        bb[i] = (long)(ntile * 128 + i * 32 + srow) * D_ + scol;
    }
    const int wr = (wv >> 1) * 64, wc = (wv & 1) * 64;
    const int fr = lane & 15, fq = lane >> 4;
    f32x4 acc[4][4] = {};
    for (int k0 = 0; k0 < D_; k0 += 64) {
        __syncthreads();
#pragma unroll
        for (int i = 0; i < 4; ++i) {
            async_load16(xb + ab[i] + k0, (char*)As + i * 4096 + wv * 1024);
            async_load16(w1t + bb[i] + k0, (char*)Bs + i * 4096 + wv * 1024);
        }
        __syncthreads();
#pragma unroll
        for (int kk = 0; kk < 64; kk += 32) {
            short8 a[4], b[4];
#pragma unroll
            for (int m = 0; m < 4; ++m)
                a[m] = *(const short8*)&As[(wr + m * 16 + fr) * 64 + kk + fq * 8];
#pragma unroll
            for (int n = 0; n < 4; ++n)
                b[n] = *(const short8*)&Bs[(wc + n * 16 + fr) * 64 + kk + fq * 8];
#pragma unroll
            for (int m = 0; m < 4; ++m)
#pragma unroll
                for (int n = 0; n < 4; ++n)
                    acc[m][n] = __builtin_amdgcn_mfma_f32_16x16x32_bf16(
                        a[m], b[n], acc[m][n], 0, 0, 0);
        }
    }
    const int orow0 = mtile * 128 + wr, ocol0 = ntile * 128 + wc;
#pragma unroll
    for (int m = 0; m < 4; ++m)
#pragma unroll
        for (int n = 0; n < 4; ++n) {
            int col = ocol0 + n * 16 + fr;
            float bias = b1[col];
#pragma unroll
            for (int j = 0; j < 4; ++j) {
                int row = orow0 + m * 16 + fq * 4 + j;
                float v = acc[m][n][j] + bias;
                float g = 0.5f * v * (1.0f + erff(v * 0.70710678118654752f));
                hid[(long)row * H_ + col] = f2b(g);
            }
        }
}

// ---------- GEMM2: out[idx[row]] = hid @ W2 + b2 (scatter, masked) ----------
// A: hid (MPAD x H_), B: w2t (D_ x H_ = N x K)
__global__ __launch_bounds__(256)
void gemm2_kernel(const u16* __restrict__ hid, const u16* __restrict__ w2t,
                  const float* __restrict__ b2, const int* __restrict__ idx,
                  const int* __restrict__ cnt, float* __restrict__ out) {
    __shared__ u16 As[128 * 64];
    __shared__ u16 Bs[128 * 64];
    const int tid = threadIdx.x;
    const int mtile = blockIdx.y, ntile = blockIdx.x;
    const int wv = tid >> 6, lane = tid & 63;
    const int srow = tid >> 3, scol = (tid & 7) * 8;
    long ab[4], bb[4];
#pragma unroll
    for (int i = 0; i < 4; ++i) {
        ab[i] = (long)(mtile * 128 + i * 32 + srow) * H_ + scol;
        bb[i] = (long)(ntile * 128 + i * 32 + srow) * H_ + scol;
    }
    const int wr = (wv >> 1) * 64, wc = (wv & 1) * 64;
    const int fr = lane & 15, fq = lane >> 4;
    f32x4 acc[4][4] = {};
    for (int k0 = 0; k0 < H_; k0 += 64) {
        __syncthreads();
#pragma unroll
        for (int i = 0; i < 4; ++i) {
            async_load16(hid + ab[i] + k0, (char*)As + i * 4096 + wv * 1024);
            async_load16(w2t + bb[i] + k0, (char*)Bs + i * 4096 + wv * 1024);
        }
        __syncthreads();
#pragma unroll
        for (int kk = 0; kk < 64; kk += 32) {
            short8 a[4], b[4];
#pragma unroll
            for (int m = 0; m < 4; ++m)
                a[m] = *(const short8*)&As[(wr + m * 16 + fr) * 64 + kk + fq * 8];
#pragma unroll
            for (int n = 0; n < 4; ++n)
                b[n] = *(const short8*)&Bs[(wc + n * 16 + fr) * 64 + kk + fq * 8];
#pragma unroll
            for (int m = 0; m < 4; ++m)
#pragma unroll
                for (int n = 0; n < 4; ++n)
                    acc[m][n] = __builtin_amdgcn_mfma_f32_16x16x32_bf16(
                        a[m], b[n], acc[m][n], 0, 0, 0);
        }
    }
    const int n_total = *cnt;
    const int orow0 = mtile * 128 + wr, ocol0 = ntile * 128 + wc;
#pragma unroll
    for (int m = 0; m < 4; ++m)
#pragma unroll
        for (int j = 0; j < 4; ++j) {
            int row = orow0 + m * 16 + fq * 4 + j;
            bool valid = row < n_total;
            long obase = valid ? (long)idx[row] * D_ : 0;
#pragma unroll
            for (int n = 0; n < 4; ++n) {
                int col = ocol0 + n * 16 + fr;
                if (valid) out[obase + col] = acc[m][n][j] + b2[col];
            }
        }
}

// ---------- launcher ----------
extern "C" void kernel_launch(void* const* d_in, const int* in_sizes, int n_in,
                              void* d_out, int out_size, void* d_ws, size_t ws_size,
                              hipStream_t stream) {
    const float* x   = (const float*)d_in[0];
    const float* w_r = (const float*)d_in[1];
    const float* b_r = (const float*)d_in[2];
    const float* W1  = (const float*)d_in[3];
    const float* b1  = (const float*)d_in[4];
    const float* W2  = (const float*)d_in[5];
    const float* b2  = (const float*)d_in[6];
    float* out = (float*)d_out;

    char* p = (char*)d_ws;
    auto alloc = [&](size_t bytes) {
        char* q = p;
        p += (bytes + 255) & ~(size_t)255;
        return q;
    };
    float* wts = (float*)alloc((size_t)NTOK * 4);
    float* thr = (float*)alloc(B_ * 4);
    int*   cnt = (int*)alloc(4);
    int*   idx = (int*)alloc((size_t)MPAD * 4);
    u16*   xb  = (u16*)alloc((size_t)NTOK * D_ * 2);
    u16*   w1t = (u16*)alloc((size_t)H_ * D_ * 2);
    u16*   w2t = (u16*)alloc((size_t)H_ * D_ * 2);
    u16*   hid = (u16*)alloc((size_t)MPAD * H_ * 2);

    init_kernel<<<MPAD / 256, 256, 0, stream>>>(idx, cnt);
    router_kernel<<<NTOK / 4, 256, 0, stream>>>(x, w_r, b_r, out, xb, wts);
    select_kernel<<<B_, 256, 0, stream>>>(wts, thr);
    compact_kernel<<<NTOK / 256, 256, 0, stream>>>(wts, thr, idx, cnt);
    transpose_kernel<<<dim3(H_ / 32, D_ / 32), 256, 0, stream>>>(W1, w1t, D_, H_);
    transpose_kernel<<<dim3(D_ / 32, H_ / 32), 256, 0, stream>>>(W2, w2t, H_, D_);
    gemm1_kernel<<<dim3(H_ / 128, MPAD / 128), 256, 0, stream>>>(xb, w1t, b1, idx, hid);
    gemm2_kernel<<<dim3(D_ / 128, MPAD / 128), 256, 0, stream>>>(hid, w2t, b2, idx, cnt, out);
}

// Round 3
// 748.158 us; speedup vs baseline: 1.0647x; 1.0647x over previous
//
#include <hip/hip_runtime.h>

typedef unsigned short u16;
typedef __attribute__((ext_vector_type(8))) short short8;
typedef __attribute__((ext_vector_type(4))) float f32x4;

#define B_ 4
#define S_ 8192
#define D_ 1024
#define H_ 4096
#define NTOK (B_*S_)        // 32768
#define MPAD 16384          // padded selected-token count (>= 4*4095)
#define KSEL 4096           // capacity * S

// ---------- helpers ----------
__device__ __forceinline__ u16 f2b(float f) {  // fp32 -> bf16 RNE
    unsigned u = __float_as_uint(f);
    unsigned r = (u + 0x7FFFu + ((u >> 16) & 1u)) >> 16;
    return (u16)r;
}

__device__ __forceinline__ void async_load16(const void* g, void* l) {
    __builtin_amdgcn_global_load_lds(
        (const __attribute__((address_space(1))) void*)g,
        (__attribute__((address_space(3))) void*)l, 16, 0, 0);
}

// ---------- init ----------
__global__ void init_kernel(int* __restrict__ idx, int* __restrict__ cnt) {
    int t = blockIdx.x * 256 + threadIdx.x;
    if (t < MPAD) idx[t] = 0;
    if (t == 0) *cnt = 0;
}

// ---------- router ----------
__global__ __launch_bounds__(256)
void router_kernel(const float* __restrict__ x, const float* __restrict__ w_r,
                   const float* __restrict__ b_r, float* __restrict__ out,
                   u16* __restrict__ xb, float* __restrict__ wts) {
    int wv = threadIdx.x >> 6, lane = threadIdx.x & 63;
    long t = (long)blockIdx.x * 4 + wv;
    const float4* xrow = (const float4*)x + t * 256;
    const float4* wr4  = (const float4*)w_r;
    float4* orow = (float4*)out + t * 256;
    double acc = 0.0;
#pragma unroll
    for (int j = 0; j < 4; ++j) {
        int e = lane + j * 64;
        float4 v = xrow[e];
        float4 w = wr4[e];
        acc += (double)v.x * w.x + (double)v.y * w.y +
               (double)v.z * w.z + (double)v.w * w.w;
        orow[e] = v;
        uint2 hv;
        hv.x = (unsigned)f2b(v.x) | ((unsigned)f2b(v.y) << 16);
        hv.y = (unsigned)f2b(v.z) | ((unsigned)f2b(v.w) << 16);
        *(uint2*)&xb[t * D_ + e * 4] = hv;
    }
#pragma unroll
    for (int off = 32; off > 0; off >>= 1) acc += __shfl_down(acc, off);
    if (lane == 0) wts[t] = (float)(acc + (double)b_r[0]);
}

// ---------- exact k-th largest per batch (radix select) ----------
__global__ void select_kernel(const float* __restrict__ w, float* __restrict__ thr) {
    int b = blockIdx.x;
    const float* wb = w + b * S_;
    __shared__ int hist[256];
    __shared__ unsigned s_prefix;
    __shared__ int s_rank;
    int tid = threadIdx.x;
    if (tid == 0) { s_prefix = 0u; s_rank = S_ - KSEL; }
    __syncthreads();
    for (int pass = 0; pass < 4; ++pass) {
        int shift = 24 - 8 * pass;
        hist[tid] = 0;
        __syncthreads();
        unsigned pfx = s_prefix;
        for (int i = tid; i < S_; i += 256) {
            unsigned u = __float_as_uint(wb[i]);
            u = (u & 0x80000000u) ? ~u : (u | 0x80000000u);
            if (pass == 0 || (u >> (shift + 8)) == pfx)
                atomicAdd(&hist[(u >> shift) & 0xFF], 1);
        }
        __syncthreads();
        if (tid == 0) {
            int r = s_rank;
            unsigned d;
            for (d = 0; d < 256; ++d) { int c = hist[d]; if (r < c) break; r -= c; }
            s_rank = r;
            s_prefix = (s_prefix << 8) | d;
        }
        __syncthreads();
    }
    if (tid == 0) {
        unsigned u = s_prefix;
        unsigned orig = (u & 0x80000000u) ? (u ^ 0x80000000u) : ~u;
        thr[b] = __uint_as_float(orig);
    }
}

// ---------- compact ----------
__global__ void compact_kernel(const float* __restrict__ w, const float* __restrict__ thr,
                               int* __restrict__ idx, int* __restrict__ cnt) {
    int t = blockIdx.x * 256 + threadIdx.x;
    int b = t >> 13;
    if (w[t] > thr[b]) {
        int p = atomicAdd(cnt, 1);
        idx[p] = t;
    }
}

// ---------- transpose + cast ----------
__global__ void transpose_kernel(const float* __restrict__ W, u16* __restrict__ Wt,
                                 int R, int C) {
    __shared__ float tile[32][33];
    int c0 = blockIdx.x * 32, r0 = blockIdx.y * 32;
    int tx = threadIdx.x & 31, ty = threadIdx.x >> 5;
#pragma unroll
    for (int i = 0; i < 32; i += 8)
        tile[ty + i][tx] = W[(long)(r0 + ty + i) * C + c0 + tx];
    __syncthreads();
#pragma unroll
    for (int i = 0; i < 32; i += 8)
        Wt[(long)(c0 + ty + i) * R + r0 + tx] = f2b(tile[tx][ty + i]);
}

// ================= 256x256 8-phase GEMM (T2+T3+T4+T5) =================
// MODE 0: A rows gathered via idx, epilogue gelu -> bf16 hid
// MODE 1: A linear (hid), epilogue scatter fp32 out[idx[row]] (row<cnt)
#define DSR(dst, off) asm volatile("ds_read_b128 %0, %1" : "=v"(dst) : "v"(off))

template<int NT, int MODE>
__global__ __launch_bounds__(512, 2)
void gemm8p(const u16* __restrict__ A, const u16* __restrict__ Bm,
            const float* __restrict__ bias, const int* __restrict__ idx,
            const int* __restrict__ cnt, void* __restrict__ outp) {
    extern __shared__ char smem[];
    constexpr int NI = NT / 2;
    constexpr long RB = (long)NT * 128;   // row bytes of A / B panels
    const int tid = threadIdx.x;
    const int lane = tid & 63;
    const int wv = tid >> 6, wm = wv >> 2, wn = wv & 3;
    const int fr = lane & 15, fq = lane >> 4;
    const int mtile = blockIdx.y, ntile = blockIdx.x;

    // ---- staging: per (h,l) pre-swizzled global sources, linear LDS dest ----
    const int rl_s = tid >> 3;                                        // 0..63
    const unsigned colb = (unsigned)(((tid & 7) * 16) ^ ((rl_s & 7) << 4));
    const char* srcA[4]; const char* srcB[4];
#pragma unroll
    for (int h = 0; h < 2; ++h)
#pragma unroll
        for (int l = 0; l < 2; ++l) {
            int rl = h * 128 + l * 64 + rl_s;
            long arow = (MODE == 0) ? (long)idx[mtile * 256 + rl]
                                    : (long)(mtile * 256 + rl);
            srcA[h * 2 + l] = (const char*)A + arow * RB + colb;
            srcB[h * 2 + l] = (const char*)Bm + (long)(ntile * 256 + rl) * RB + colb;
        }
    const unsigned dstOff = (unsigned)((tid >> 3) * 128 + (tid & 7) * 16);

    // ---- swizzled LDS read offsets ----
    const unsigned ldsbase = (unsigned)(unsigned long long)(void*)smem;
    const unsigned c0 = (unsigned)((fq * 16) ^ ((fr & 7) << 4));
    const unsigned c1 = c0 ^ 64u;
    const unsigned offA = ldsbase + (unsigned)(wm * 16384 + fr * 128);
    const unsigned offB = ldsbase + 65536u + (unsigned)(wn * 8192 + fr * 128);

#define STAGE_A(t, h, db) { \
    async_load16(srcA[(h)*2+0] + (long)(t)*128, smem + (db)*32768 + (h)*16384 + dstOff); \
    async_load16(srcA[(h)*2+1] + (long)(t)*128, smem + (db)*32768 + (h)*16384 + 8192 + dstOff); }
#define STAGE_B(t, h, db) { \
    async_load16(srcB[(h)*2+0] + (long)(t)*128, smem + 65536 + (db)*32768 + (h)*16384 + dstOff); \
    async_load16(srcB[(h)*2+1] + (long)(t)*128, smem + 65536 + (db)*32768 + (h)*16384 + 8192 + dstOff); }

    f32x4 acc[8][4] = {};
    short8 a[2][2], b[4][2];

    // prologue: stage A(0),B(0) -> dbuf0; B(1) -> dbuf1; keep B(1) in flight
    STAGE_A(0, 0, 0); STAGE_A(0, 1, 0);
    STAGE_B(0, 0, 0); STAGE_B(0, 1, 0);
    STAGE_B(1, 0, 1); STAGE_B(1, 1, 1);
    asm volatile("s_waitcnt vmcnt(4)" ::: "memory");
    __builtin_amdgcn_s_barrier();
    __builtin_amdgcn_sched_barrier(0);

#define PHASE(P, STAGE_STMT) { \
    constexpr int pp = (P) & 3; \
    constexpr unsigned rdb = ((P) < 4) ? 0u : 32768u; \
    if constexpr (pp == 0) { \
        _Pragma("unroll") \
        for (int n = 0; n < 4; ++n) { \
            DSR(b[n][0], offB + rdb + n * 2048 + c0); \
            DSR(b[n][1], offB + rdb + n * 2048 + c1); \
        } \
    } \
    DSR(a[0][0], offA + rdb + (2*pp)   * 2048 + c0); \
    DSR(a[0][1], offA + rdb + (2*pp)   * 2048 + c1); \
    DSR(a[1][0], offA + rdb + (2*pp+1) * 2048 + c0); \
    DSR(a[1][1], offA + rdb + (2*pp+1) * 2048 + c1); \
    STAGE_STMT; \
    __builtin_amdgcn_sched_barrier(0); \
    __builtin_amdgcn_s_barrier(); \
    asm volatile("s_waitcnt lgkmcnt(0)" ::: "memory"); \
    __builtin_amdgcn_sched_barrier(0); \
    __builtin_amdgcn_s_setprio(1); \
    _Pragma("unroll") \
    for (int kk = 0; kk < 2; ++kk) \
        _Pragma("unroll") \
        for (int mm = 0; mm < 2; ++mm) \
            _Pragma("unroll") \
            for (int n = 0; n < 4; ++n) \
                acc[2*pp+mm][n] = __builtin_amdgcn_mfma_f32_16x16x32_bf16( \
                    a[mm][kk], b[n][kk], acc[2*pp+mm][n], 0, 0, 0); \
    __builtin_amdgcn_s_setprio(0); \
    __builtin_amdgcn_sched_barrier(0); \
    if constexpr (pp == 3) asm volatile("s_waitcnt vmcnt(4)" ::: "memory"); \
    __builtin_amdgcn_s_barrier(); \
    __builtin_amdgcn_sched_barrier(0); }

    for (int i = 0; i < NI; ++i) {
        const int t0 = 2 * i;
        const int tB0 = (t0 + 2 >= NT) ? t0 : t0 + 2;       // parity-preserving clamp
        const int tB1 = (t0 + 3 >= NT) ? t0 + 1 : t0 + 3;
        PHASE(0, STAGE_A(t0 + 1, 0, 1));
        PHASE(1, STAGE_A(t0 + 1, 1, 1));
        PHASE(2, STAGE_B(tB0, 0, 0));
        PHASE(3, STAGE_B(tB0, 1, 0));
        PHASE(4, STAGE_A(tB0, 0, 0));
        PHASE(5, STAGE_A(tB0, 1, 0));
        PHASE(6, STAGE_B(tB1, 0, 1));
        PHASE(7, STAGE_B(tB1, 1, 1));
    }
    asm volatile("s_waitcnt vmcnt(0)" ::: "memory");   // drain DMA before LDS teardown

    // ---- epilogue ----
    const int orow0 = mtile * 256 + wm * 128;
    const int ocol0 = ntile * 256 + wn * 64;
    if constexpr (MODE == 0) {
        u16* hidp = (u16*)outp;
#pragma unroll
        for (int m = 0; m < 8; ++m)
#pragma unroll
            for (int n = 0; n < 4; ++n) {
                const int col = ocol0 + n * 16 + fr;
                const float bv = bias[col];
#pragma unroll
                for (int j = 0; j < 4; ++j) {
                    const int row = orow0 + m * 16 + fq * 4 + j;
                    float v = acc[m][n][j] + bv;
                    float g = 0.5f * v * (1.0f + erff(v * 0.70710678118654752f));
                    hidp[(long)row * H_ + col] = f2b(g);
                }
            }
    } else {
        float* op = (float*)outp;
        const int ncnt = *cnt;
#pragma unroll
        for (int m = 0; m < 8; ++m)
#pragma unroll
            for (int j = 0; j < 4; ++j) {
                const int row = orow0 + m * 16 + fq * 4 + j;
                if (row < ncnt) {
                    const long ob = (long)idx[row] * D_;
#pragma unroll
                    for (int n = 0; n < 4; ++n) {
                        const int col = ocol0 + n * 16 + fr;
                        op[ob + col] = acc[m][n][j] + bias[col];
                    }
                }
            }
    }
#undef PHASE
#undef STAGE_A
#undef STAGE_B
}

// ---------- launcher ----------
extern "C" void kernel_launch(void* const* d_in, const int* in_sizes, int n_in,
                              void* d_out, int out_size, void* d_ws, size_t ws_size,
                              hipStream_t stream) {
    const float* x   = (const float*)d_in[0];
    const float* w_r = (const float*)d_in[1];
    const float* b_r = (const float*)d_in[2];
    const float* W1  = (const float*)d_in[3];
    const float* b1  = (const float*)d_in[4];
    const float* W2  = (const float*)d_in[5];
    const float* b2  = (const float*)d_in[6];
    float* out = (float*)d_out;

    char* p = (char*)d_ws;
    auto alloc = [&](size_t bytes) {
        char* q = p;
        p += (bytes + 255) & ~(size_t)255;
        return q;
    };
    float* wts = (float*)alloc((size_t)NTOK * 4);
    float* thr = (float*)alloc(B_ * 4);
    int*   cnt = (int*)alloc(4);
    int*   idx = (int*)alloc((size_t)MPAD * 4);
    u16*   xb  = (u16*)alloc((size_t)NTOK * D_ * 2);
    u16*   w1t = (u16*)alloc((size_t)H_ * D_ * 2);
    u16*   w2t = (u16*)alloc((size_t)H_ * D_ * 2);
    u16*   hid = (u16*)alloc((size_t)MPAD * H_ * 2);

    auto k1 = gemm8p<16, 0>;
    auto k2 = gemm8p<64, 1>;
    (void)hipFuncSetAttribute((const void*)k1, hipFuncAttributeMaxDynamicSharedMemorySize, 131072);
    (void)hipFuncSetAttribute((const void*)k2, hipFuncAttributeMaxDynamicSharedMemorySize, 131072);

    init_kernel<<<MPAD / 256, 256, 0, stream>>>(idx, cnt);
    router_kernel<<<NTOK / 4, 256, 0, stream>>>(x, w_r, b_r, out, xb, wts);
    select_kernel<<<B_, 256, 0, stream>>>(wts, thr);
    compact_kernel<<<NTOK / 256, 256, 0, stream>>>(wts, thr, idx, cnt);
    transpose_kernel<<<dim3(H_ / 32, D_ / 32), 256, 0, stream>>>(W1, w1t, D_, H_);
    transpose_kernel<<<dim3(D_ / 32, H_ / 32), 256, 0, stream>>>(W2, w2t, H_, D_);
    k1<<<dim3(H_ / 256, MPAD / 256), 512, 131072, stream>>>(xb, w1t, b1, idx, nullptr, hid);
    k2<<<dim3(D_ / 256, MPAD / 256), 512, 131072, stream>>>(hid, w2t, b2, idx, cnt, out);
}

// Round 5
// 613.666 us; speedup vs baseline: 1.2981x; 1.2192x over previous
//
#include <hip/hip_runtime.h>

typedef unsigned short u16;
typedef __attribute__((ext_vector_type(8))) short short8;
typedef __attribute__((ext_vector_type(4))) float f32x4;

#define B_ 4
#define S_ 8192
#define D_ 1024
#define H_ 4096
#define NTOK (B_*S_)
#define MPAD 16384
#define KSEL 4096

// ---------- helpers ----------
__device__ __forceinline__ u16 f2b(float f) {  // fp32 -> bf16 RNE
    unsigned u = __float_as_uint(f);
    unsigned r = (u + 0x7FFFu + ((u >> 16) & 1u)) >> 16;
    return (u16)r;
}

__device__ __forceinline__ void async_load16(const void* g, void* l) {
    __builtin_amdgcn_global_load_lds(
        (const __attribute__((address_space(1))) void*)g,
        (__attribute__((address_space(3))) void*)l, 16, 0, 0);
}

// ---------- init ----------
__global__ void init_kernel(int* __restrict__ idx, int* __restrict__ cnt) {
    int t = blockIdx.x * 256 + threadIdx.x;
    if (t < MPAD) idx[t] = 0;
    if (t == 0) *cnt = 0;
}

// ---------- router ----------
__global__ __launch_bounds__(256)
void router_kernel(const float* __restrict__ x, const float* __restrict__ w_r,
                   const float* __restrict__ b_r, float* __restrict__ out,
                   u16* __restrict__ xb, float* __restrict__ wts) {
    int wv = threadIdx.x >> 6, lane = threadIdx.x & 63;
    long t = (long)blockIdx.x * 4 + wv;
    const float4* xrow = (const float4*)x + t * 256;
    const float4* wr4  = (const float4*)w_r;
    float4* orow = (float4*)out + t * 256;
    double acc = 0.0;
#pragma unroll
    for (int j = 0; j < 4; ++j) {
        int e = lane + j * 64;
        float4 v = xrow[e];
        float4 w = wr4[e];
        acc += (double)v.x * w.x + (double)v.y * w.y +
               (double)v.z * w.z + (double)v.w * w.w;
        orow[e] = v;
        uint2 hv;
        hv.x = (unsigned)f2b(v.x) | ((unsigned)f2b(v.y) << 16);
        hv.y = (unsigned)f2b(v.z) | ((unsigned)f2b(v.w) << 16);
        *(uint2*)&xb[t * D_ + e * 4] = hv;
    }
#pragma unroll
    for (int off = 32; off > 0; off >>= 1) acc += __shfl_down(acc, off);
    if (lane == 0) wts[t] = (float)(acc + (double)b_r[0]);
}

// ---------- exact k-th largest per batch (radix select) ----------
__global__ void select_kernel(const float* __restrict__ w, float* __restrict__ thr) {
    int b = blockIdx.x;
    const float* wb = w + b * S_;
    __shared__ int hist[256];
    __shared__ unsigned s_prefix;
    __shared__ int s_rank;
    int tid = threadIdx.x;
    if (tid == 0) { s_prefix = 0u; s_rank = S_ - KSEL; }
    __syncthreads();
    for (int pass = 0; pass < 4; ++pass) {
        int shift = 24 - 8 * pass;
        hist[tid] = 0;
        __syncthreads();
        unsigned pfx = s_prefix;
        for (int i = tid; i < S_; i += 256) {
            unsigned u = __float_as_uint(wb[i]);
            u = (u & 0x80000000u) ? ~u : (u | 0x80000000u);
            if (pass == 0 || (u >> (shift + 8)) == pfx)
                atomicAdd(&hist[(u >> shift) & 0xFF], 1);
        }
        __syncthreads();
        if (tid == 0) {
            int r = s_rank;
            unsigned d;
            for (d = 0; d < 256; ++d) { int c = hist[d]; if (r < c) break; r -= c; }
            s_rank = r;
            s_prefix = (s_prefix << 8) | d;
        }
        __syncthreads();
    }
    if (tid == 0) {
        unsigned u = s_prefix;
        unsigned orig = (u & 0x80000000u) ? (u ^ 0x80000000u) : ~u;
        thr[b] = __uint_as_float(orig);
    }
}

// ---------- compact ----------
__global__ void compact_kernel(const float* __restrict__ w, const float* __restrict__ thr,
                               int* __restrict__ idx, int* __restrict__ cnt) {
    int t = blockIdx.x * 256 + threadIdx.x;
    int b = t >> 13;
    if (w[t] > thr[b]) {
        int p = atomicAdd(cnt, 1);
        idx[p] = t;
    }
}

// ---------- transpose + cast ----------
__global__ void transpose_kernel(const float* __restrict__ W, u16* __restrict__ Wt,
                                 int R, int C) {
    __shared__ float tile[32][33];
    int c0 = blockIdx.x * 32, r0 = blockIdx.y * 32;
    int tx = threadIdx.x & 31, ty = threadIdx.x >> 5;
#pragma unroll
    for (int i = 0; i < 32; i += 8)
        tile[ty + i][tx] = W[(long)(r0 + ty + i) * C + c0 + tx];
    __syncthreads();
#pragma unroll
    for (int i = 0; i < 32; i += 8)
        Wt[(long)(c0 + ty + i) * R + r0 + tx] = f2b(tile[tx][ty + i]);
}

// ================= 256x256 8-phase GEMM (T1+T2+T3+T4+T5) =================
// Compiler-scheduled LDS reads (plain loads, folded offsets); raw barriers;
// counted vmcnt(4); setprio around MFMA clusters. MODE 0: gathered A + gelu
// -> bf16 hid via LDS-coalesced epilogue. MODE 1: linear A + fp32 scatter.
template<int NT, int NTILES, int MODE>
__global__ __launch_bounds__(512, 2)
void gemm8p(const u16* __restrict__ A, const u16* __restrict__ Bm,
            const float* __restrict__ bias, const int* __restrict__ idx,
            const int* __restrict__ cnt, void* __restrict__ outp) {
    extern __shared__ char smem[];
    constexpr int NI = NT / 2;
    constexpr long RB = (long)NT * 128;     // row bytes of A / B panels
    constexpr int LOG_NT = (NTILES == 16) ? 4 : 2;
    const int tid = threadIdx.x;
    const int lane = tid & 63;
    const int wv = tid >> 6, wm = wv >> 2, wn = wv & 3;
    const int fr = lane & 15, fq = lane >> 4;

    // T1: bijective XCD-chunked swizzle (NWG % 8 == 0)
    constexpr int NWG = NTILES * 64;
    constexpr int QX = NWG / 8;
    const int wg = blockIdx.x + blockIdx.y * NTILES;
    const int swz = (wg & 7) * QX + (wg >> 3);
    const int ntile = swz & (NTILES - 1);
    const int mtile = swz >> LOG_NT;

    // ---- staging: pre-swizzled global sources, linear LDS dest ----
    const int rl_s = tid >> 3;
    const unsigned colb = (unsigned)(((tid & 7) * 16) ^ ((rl_s & 7) << 4));
    const char* srcA[4]; const char* srcB[4];
#pragma unroll
    for (int h = 0; h < 2; ++h)
#pragma unroll
        for (int l = 0; l < 2; ++l) {
            int rl = h * 128 + l * 64 + rl_s;
            long arow = (MODE == 0) ? (long)idx[mtile * 256 + rl]
                                    : (long)(mtile * 256 + rl);
            srcA[h * 2 + l] = (const char*)A + arow * RB + colb;
            srcB[h * 2 + l] = (const char*)Bm + (long)(ntile * 256 + rl) * RB + colb;
        }
    const unsigned dstOff = (unsigned)((tid >> 3) * 128 + (tid & 7) * 16);

    // ---- LDS read bases (swizzled) ----
    const unsigned arowb = (unsigned)((wm * 128 + fr) * 128);
    const unsigned browb = (unsigned)((wn * 64 + fr) * 128);
    unsigned ck[2];
    ck[0] = (unsigned)((fq * 16) ^ ((fr & 7) << 4));
    ck[1] = ck[0] ^ 64u;

#define STAGE_A(t, h, db) { \
    async_load16(srcA[(h)*2+0] + (long)(t)*128, smem + (db)*32768 + (h)*16384 + dstOff); \
    async_load16(srcA[(h)*2+1] + (long)(t)*128, smem + (db)*32768 + (h)*16384 + 8192 + dstOff); }
#define STAGE_B(t, h, db) { \
    async_load16(srcB[(h)*2+0] + (long)(t)*128, smem + 65536 + (db)*32768 + (h)*16384 + dstOff); \
    async_load16(srcB[(h)*2+1] + (long)(t)*128, smem + 65536 + (db)*32768 + (h)*16384 + 8192 + dstOff); }
#define BAR() __builtin_amdgcn_s_barrier()
#define VM4() asm volatile("s_waitcnt vmcnt(4)" ::: "memory")

    f32x4 acc[8][4] = {};
    short8 bfr[2][4];

    // prologue: A(0),B(0) -> db0; B(1) -> db1 (stays in flight)
    STAGE_A(0, 0, 0); STAGE_A(0, 1, 0);
    STAGE_B(0, 0, 0); STAGE_B(0, 1, 0);
    STAGE_B(1, 0, 1); STAGE_B(1, 1, 1);
    asm volatile("s_waitcnt vmcnt(4)" ::: "memory");
    BAR();

    // phase: {4 a-reads [+4 b-reads] || 1 stage} -> bar -> prio1 16xMFMA prio0
#define PHASE(DB, KK, SLAB, BLOAD, STAGE_STMT) { \
    constexpr unsigned rdb = (DB) * 32768u; \
    if (BLOAD) { \
        _Pragma("unroll") \
        for (int n = 0; n < 4; ++n) \
            bfr[KK][n] = *(const short8*)(smem + (65536u + rdb + (unsigned)(n) * 2048u) + browb + ck[KK]); \
    } \
    short8 afr[4]; \
    _Pragma("unroll") \
    for (int r = 0; r < 4; ++r) \
        afr[r] = *(const short8*)(smem + (rdb + (unsigned)((SLAB) + r) * 2048u) + arowb + ck[KK]); \
    STAGE_STMT; \
    BAR(); \
    __builtin_amdgcn_s_setprio(1); \
    _Pragma("unroll") \
    for (int r = 0; r < 4; ++r) \
        _Pragma("unroll") \
        for (int n = 0; n < 4; ++n) \
            acc[(SLAB) + r][n] = __builtin_amdgcn_mfma_f32_16x16x32_bf16( \
                afr[r], bfr[KK][n], acc[(SLAB) + r][n], 0, 0, 0); \
    __builtin_amdgcn_s_setprio(0); }

    for (int i = 0; i < NI; ++i) {
        const int t0 = 2 * i;
        const int tA1 = t0 + 1;
        const int tB2 = (t0 + 2 >= NT) ? t0     : t0 + 2;   // parity-preserving clamp
        const int tB3 = (t0 + 3 >= NT) ? t0 + 1 : t0 + 3;
        PHASE(0, 0, 0, true,  STAGE_A(tA1, 0, 1)); BAR();
        PHASE(0, 1, 0, true,  STAGE_A(tA1, 1, 1)); BAR();
        PHASE(0, 0, 4, false, STAGE_B(tB2, 0, 0)); BAR();
        PHASE(0, 1, 4, false, STAGE_B(tB2, 1, 0)); VM4(); BAR();
        PHASE(1, 0, 0, true,  STAGE_A(tB2, 0, 0)); BAR();
        PHASE(1, 1, 0, true,  STAGE_A(tB2, 1, 0)); BAR();
        PHASE(1, 0, 4, false, STAGE_B(tB3, 0, 1)); BAR();
        PHASE(1, 1, 4, false, STAGE_B(tB3, 1, 1)); VM4(); BAR();
    }
    asm volatile("s_waitcnt vmcnt(0)" ::: "memory");   // drain all DMA (per-wave)
    BAR();                                              // everyone drained

    // ---- epilogue ----
    if constexpr (MODE == 0) {
        // gelu (tanh form) -> bf16, scatter into swizzled LDS tile, coalesced store
        u16* lt = (u16*)smem;
#pragma unroll
        for (int m = 0; m < 8; ++m)
#pragma unroll
            for (int n = 0; n < 4; ++n) {
                const int lcol = wn * 64 + n * 16 + fr;
                const float bv = bias[ntile * 256 + lcol];
#pragma unroll
                for (int j = 0; j < 4; ++j) {
                    const int lrow = wm * 128 + m * 16 + fq * 4 + j;
                    float v = acc[m][n][j] + bv;
                    float z = 1.5957691216f * (v + 0.044715f * v * v * v);
                    float g = v / (1.0f + __expf(-z));
                    lt[lrow * 256 + (lcol ^ ((lrow & 7) << 3))] = f2b(g);
                }
            }
        asm volatile("s_waitcnt lgkmcnt(0)" ::: "memory");
        BAR();
        u16* hidp = (u16*)outp;
        const long gbase = (long)(mtile * 256) * H_ + ntile * 256;
#pragma unroll
        for (int it = 0; it < 16; ++it) {
            const unsigned off = (unsigned)it * 8192u + (unsigned)tid * 16u;
            const int lrow = off >> 9;
            const unsigned lcolb = off & 511u;
            short8 vv = *(const short8*)(smem + (unsigned)(lrow << 9) + (lcolb ^ ((unsigned)(lrow & 7) << 4)));
            *(short8*)((char*)hidp + (gbase + (long)lrow * H_) * 2 + lcolb) = vv;
        }
    } else {
        float* op = (float*)outp;
        const int ncnt = *cnt;
        const int orow0 = mtile * 256 + wm * 128;
        const int ocol0 = ntile * 256 + wn * 64;
#pragma unroll
        for (int m = 0; m < 8; ++m)
#pragma unroll
            for (int j = 0; j < 4; ++j) {
                const int row = orow0 + m * 16 + fq * 4 + j;
                if (row < ncnt) {
                    const long ob = (long)idx[row] * D_;
#pragma unroll
                    for (int n = 0; n < 4; ++n) {
                        const int col = ocol0 + n * 16 + fr;
                        op[ob + col] = acc[m][n][j] + bias[col];
                    }
                }
            }
    }
#undef PHASE
#undef STAGE_A
#undef STAGE_B
#undef BAR
#undef VM4
}

// ---------- launcher ----------
extern "C" void kernel_launch(void* const* d_in, const int* in_sizes, int n_in,
                              void* d_out, int out_size, void* d_ws, size_t ws_size,
                              hipStream_t stream) {
    const float* x   = (const float*)d_in[0];
    const float* w_r = (const float*)d_in[1];
    const float* b_r = (const float*)d_in[2];
    const float* W1  = (const float*)d_in[3];
    const float* b1  = (const float*)d_in[4];
    const float* W2  = (const float*)d_in[5];
    const float* b2  = (const float*)d_in[6];
    float* out = (float*)d_out;

    char* p = (char*)d_ws;
    auto alloc = [&](size_t bytes) {
        char* q = p;
        p += (bytes + 255) & ~(size_t)255;
        return q;
    };
    float* wts = (float*)alloc((size_t)NTOK * 4);
    float* thr = (float*)alloc(B_ * 4);
    int*   cnt = (int*)alloc(4);
    int*   idx = (int*)alloc((size_t)MPAD * 4);
    u16*   xb  = (u16*)alloc((size_t)NTOK * D_ * 2);
    u16*   w1t = (u16*)alloc((size_t)H_ * D_ * 2);
    u16*   w2t = (u16*)alloc((size_t)H_ * D_ * 2);
    u16*   hid = (u16*)alloc((size_t)MPAD * H_ * 2);

    auto k1 = gemm8p<16, 16, 0>;
    auto k2 = gemm8p<64, 4, 1>;
    (void)hipFuncSetAttribute((const void*)k1, hipFuncAttributeMaxDynamicSharedMemorySize, 131072);
    (void)hipFuncSetAttribute((const void*)k2, hipFuncAttributeMaxDynamicSharedMemorySize, 131072);

    init_kernel<<<MPAD / 256, 256, 0, stream>>>(idx, cnt);
    router_kernel<<<NTOK / 4, 256, 0, stream>>>(x, w_r, b_r, out, xb, wts);
    select_kernel<<<B_, 256, 0, stream>>>(wts, thr);
    compact_kernel<<<NTOK / 256, 256, 0, stream>>>(wts, thr, idx, cnt);
    transpose_kernel<<<dim3(H_ / 32, D_ / 32), 256, 0, stream>>>(W1, w1t, D_, H_);
    transpose_kernel<<<dim3(D_ / 32, H_ / 32), 256, 0, stream>>>(W2, w2t, H_, D_);
    k1<<<dim3(16, 64), 512, 131072, stream>>>(xb, w1t, b1, idx, nullptr, hid);
    k2<<<dim3(4, 64), 512, 131072, stream>>>(hid, w2t, b2, idx, cnt, out);
}

// Round 8
// 580.313 us; speedup vs baseline: 1.3727x; 1.0575x over previous
//
#include <hip/hip_runtime.h>

typedef unsigned short u16;
typedef __attribute__((ext_vector_type(8))) short short8;
typedef __attribute__((ext_vector_type(4))) float f32x4;

#define B_ 4
#define S_ 8192
#define D_ 1024
#define H_ 4096
#define NTOK (B_*S_)
#define MPAD 16384
#define KSEL 4096

// ---------- helpers ----------
__device__ __forceinline__ u16 f2b(float f) {  // fp32 -> bf16 RNE
    unsigned u = __float_as_uint(f);
    unsigned r = (u + 0x7FFFu + ((u >> 16) & 1u)) >> 16;
    return (u16)r;
}

__device__ __forceinline__ void async_load16(const void* g, void* l) {
    __builtin_amdgcn_global_load_lds(
        (const __attribute__((address_space(1))) void*)g,
        (__attribute__((address_space(3))) void*)l, 16, 0, 0);
}

// ---------- init ----------
__global__ void init_kernel(int* __restrict__ idx, int* __restrict__ cnt) {
    int t = blockIdx.x * 256 + threadIdx.x;
    if (t < MPAD) idx[t] = 0;
    if (t == 0) *cnt = 0;
}

// ---------- router ----------
__global__ __launch_bounds__(256)
void router_kernel(const float* __restrict__ x, const float* __restrict__ w_r,
                   const float* __restrict__ b_r, float* __restrict__ out,
                   u16* __restrict__ xb, float* __restrict__ wts) {
    int wv = threadIdx.x >> 6, lane = threadIdx.x & 63;
    long t = (long)blockIdx.x * 4 + wv;
    const float4* xrow = (const float4*)x + t * 256;
    const float4* wr4  = (const float4*)w_r;
    float4* orow = (float4*)out + t * 256;
    double acc = 0.0;
#pragma unroll
    for (int j = 0; j < 4; ++j) {
        int e = lane + j * 64;
        float4 v = xrow[e];
        float4 w = wr4[e];
        acc += (double)v.x * w.x + (double)v.y * w.y +
               (double)v.z * w.z + (double)v.w * w.w;
        orow[e] = v;
        uint2 hv;
        hv.x = (unsigned)f2b(v.x) | ((unsigned)f2b(v.y) << 16);
        hv.y = (unsigned)f2b(v.z) | ((unsigned)f2b(v.w) << 16);
        *(uint2*)&xb[t * D_ + e * 4] = hv;
    }
#pragma unroll
    for (int off = 32; off > 0; off >>= 1) acc += __shfl_down(acc, off);
    if (lane == 0) wts[t] = (float)(acc + (double)b_r[0]);
}

// ---------- exact k-th largest per batch: 32-step bisection, no atomics ----------
// Finds res = max{t : count(u > t) >= KSEL} on the monotonic uint map;
// then V_u = res+1 is exactly the KSEL-th largest value. thr = unmap(V_u).
__global__ __launch_bounds__(256)
void select_kernel(const float* __restrict__ w, float* __restrict__ thr) {
    int b = blockIdx.x;
    const float* wb = w + b * S_;
    int tid = threadIdx.x;
    unsigned uv[32];
#pragma unroll
    for (int j = 0; j < 32; ++j) {
        unsigned u = __float_as_uint(wb[tid + j * 256]);
        uv[j] = (u & 0x80000000u) ? ~u : (u | 0x80000000u);
    }
    __shared__ int partial[4];
    unsigned res = 0u;
    for (int bit = 31; bit >= 0; --bit) {
        unsigned cand = res | (1u << bit);
        int c = 0;
#pragma unroll
        for (int j = 0; j < 32; ++j) c += (uv[j] > cand) ? 1 : 0;
#pragma unroll
        for (int off = 32; off > 0; off >>= 1) c += __shfl_down(c, off);
        if ((tid & 63) == 0) partial[tid >> 6] = c;
        __syncthreads();
        int tot = partial[0] + partial[1] + partial[2] + partial[3];
        if (tot >= KSEL) res = cand;
        __syncthreads();
    }
    if (tid == 0) {
        unsigned vu = res + 1u;
        unsigned orig = (vu & 0x80000000u) ? (vu ^ 0x80000000u) : ~vu;
        thr[b] = __uint_as_float(orig);
    }
}

// ---------- compact ----------
__global__ void compact_kernel(const float* __restrict__ w, const float* __restrict__ thr,
                               int* __restrict__ idx, int* __restrict__ cnt) {
    int t = blockIdx.x * 256 + threadIdx.x;
    int b = t >> 13;
    if (w[t] > thr[b]) {
        int p = atomicAdd(cnt, 1);
        idx[p] = t;
    }
}

// ---------- transpose + cast ----------
__global__ void transpose_kernel(const float* __restrict__ W, u16* __restrict__ Wt,
                                 int R, int C) {
    __shared__ float tile[32][33];
    int c0 = blockIdx.x * 32, r0 = blockIdx.y * 32;
    int tx = threadIdx.x & 31, ty = threadIdx.x >> 5;
#pragma unroll
    for (int i = 0; i < 32; i += 8)
        tile[ty + i][tx] = W[(long)(r0 + ty + i) * C + c0 + tx];
    __syncthreads();
#pragma unroll
    for (int i = 0; i < 32; i += 8)
        Wt[(long)(c0 + ty + i) * R + r0 + tx] = f2b(tile[tx][ty + i]);
}

// ================= 256x256 8-phase GEMM (T1+T2+T3+T4+T5) =================
// Plain-C++ LDS reads pinned before the phase barrier by ONE sched_barrier(0)
// (m201 ordering without m141 over-pinning); raw barriers; counted vmcnt(4);
// setprio around MFMA. MODE 0: gathered A + gelu -> bf16 hid (LDS-coalesced
// epilogue). MODE 1: linear A + fp32 scatter.
template<int NT, int NTILES, int MODE>
__global__ __launch_bounds__(512, 2)
void gemm8p(const u16* __restrict__ A, const u16* __restrict__ Bm,
            const float* __restrict__ bias, const int* __restrict__ idx,
            const int* __restrict__ cnt, void* __restrict__ outp) {
    extern __shared__ char smem[];
    constexpr int NI = NT / 2;
    constexpr long RB = (long)NT * 128;     // row bytes of A / B panels
    constexpr int LOG_NT = (NTILES == 16) ? 4 : 2;
    const int tid = threadIdx.x;
    const int lane = tid & 63;
    const int wv = tid >> 6, wm = wv >> 2, wn = wv & 3;
    const int fr = lane & 15, fq = lane >> 4;

    // T1: bijective XCD-chunked swizzle (NWG % 8 == 0)
    constexpr int NWG = NTILES * 64;
    constexpr int QX = NWG / 8;
    const int wg = blockIdx.x + blockIdx.y * NTILES;
    const int swz = (wg & 7) * QX + (wg >> 3);
    const int ntile = swz & (NTILES - 1);
    const int mtile = swz >> LOG_NT;

    // ---- staging: pre-swizzled global sources, linear LDS dest ----
    const int rl_s = tid >> 3;
    const unsigned colb = (unsigned)(((tid & 7) * 16) ^ ((rl_s & 7) << 4));
    const char* srcA[4]; const char* srcB[4];
#pragma unroll
    for (int h = 0; h < 2; ++h)
#pragma unroll
        for (int l = 0; l < 2; ++l) {
            int rl = h * 128 + l * 64 + rl_s;
            long arow = (MODE == 0) ? (long)idx[mtile * 256 + rl]
                                    : (long)(mtile * 256 + rl);
            srcA[h * 2 + l] = (const char*)A + arow * RB + colb;
            srcB[h * 2 + l] = (const char*)Bm + (long)(ntile * 256 + rl) * RB + colb;
        }
    const unsigned dstOff = (unsigned)((tid >> 3) * 128 + (tid & 7) * 16);

    // ---- LDS read bases (swizzled) ----
    const unsigned arowb = (unsigned)((wm * 128 + fr) * 128);
    const unsigned browb = (unsigned)((wn * 64 + fr) * 128);
    unsigned ck[2];
    ck[0] = (unsigned)((fq * 16) ^ ((fr & 7) << 4));
    ck[1] = ck[0] ^ 64u;

#define STAGE_A(t, h, db) { \
    async_load16(srcA[(h)*2+0] + (long)(t)*128, smem + (db)*32768 + (h)*16384 + dstOff); \
    async_load16(srcA[(h)*2+1] + (long)(t)*128, smem + (db)*32768 + (h)*16384 + 8192 + dstOff); }
#define STAGE_B(t, h, db) { \
    async_load16(srcB[(h)*2+0] + (long)(t)*128, smem + 65536 + (db)*32768 + (h)*16384 + dstOff); \
    async_load16(srcB[(h)*2+1] + (long)(t)*128, smem + 65536 + (db)*32768 + (h)*16384 + 8192 + dstOff); }
#define BAR() __builtin_amdgcn_s_barrier()
#define VM4() asm volatile("s_waitcnt vmcnt(4)" ::: "memory")

    f32x4 acc[8][4] = {};
    short8 bfr[2][4];

    // prologue: A(0),B(0) -> db0; B(1) -> db1 (stays in flight)
    STAGE_A(0, 0, 0); STAGE_A(0, 1, 0);
    STAGE_B(0, 0, 0); STAGE_B(0, 1, 0);
    STAGE_B(1, 0, 1); STAGE_B(1, 1, 1);
    asm volatile("s_waitcnt vmcnt(4)" ::: "memory");
    BAR();

    // phase: {4 a-reads [+4 b-reads] || 1 stage} -> pin -> bar -> prio1 16xMFMA prio0
#define PHASE(DB, KK, SLAB, BLOAD, STAGE_STMT) { \
    constexpr unsigned rdb = (DB) * 32768u; \
    if (BLOAD) { \
        _Pragma("unroll") \
        for (int n = 0; n < 4; ++n) \
            bfr[KK][n] = *(const short8*)(smem + (65536u + rdb + (unsigned)(n) * 2048u) + browb + ck[KK]); \
    } \
    short8 afr[4]; \
    _Pragma("unroll") \
    for (int r = 0; r < 4; ++r) \
        afr[r] = *(const short8*)(smem + (rdb + (unsigned)((SLAB) + r) * 2048u) + arowb + ck[KK]); \
    STAGE_STMT; \
    __builtin_amdgcn_sched_barrier(0); \
    BAR(); \
    __builtin_amdgcn_s_setprio(1); \
    _Pragma("unroll") \
    for (int r = 0; r < 4; ++r) \
        _Pragma("unroll") \
        for (int n = 0; n < 4; ++n) \
            acc[(SLAB) + r][n] = __builtin_amdgcn_mfma_f32_16x16x32_bf16( \
                afr[r], bfr[KK][n], acc[(SLAB) + r][n], 0, 0, 0); \
    __builtin_amdgcn_s_setprio(0); }

    for (int i = 0; i < NI; ++i) {
        const int t0 = 2 * i;
        const int tA1 = t0 + 1;
        const int tB2 = (t0 + 2 >= NT) ? t0     : t0 + 2;   // parity-preserving clamp
        const int tB3 = (t0 + 3 >= NT) ? t0 + 1 : t0 + 3;
        PHASE(0, 0, 0, true,  STAGE_A(tA1, 0, 1)); BAR();
        PHASE(0, 1, 0, true,  STAGE_A(tA1, 1, 1)); BAR();
        PHASE(0, 0, 4, false, STAGE_B(tB2, 0, 0)); BAR();
        PHASE(0, 1, 4, false, STAGE_B(tB2, 1, 0)); VM4(); BAR();
        PHASE(1, 0, 0, true,  STAGE_A(tB2, 0, 0)); BAR();
        PHASE(1, 1, 0, true,  STAGE_A(tB2, 1, 0)); BAR();
        PHASE(1, 0, 4, false, STAGE_B(tB3, 0, 1)); BAR();
        PHASE(1, 1, 4, false, STAGE_B(tB3, 1, 1)); VM4(); BAR();
    }
    asm volatile("s_waitcnt vmcnt(0)" ::: "memory");   // drain all DMA (per-wave)
    BAR();                                              // everyone drained

    // ---- epilogue ----
    if constexpr (MODE == 0) {
        // gelu (tanh form, exp2-folded) -> bf16, swizzled LDS tile, coalesced store
        u16* lt = (u16*)smem;
#pragma unroll
        for (int m = 0; m < 8; ++m)
#pragma unroll
            for (int n = 0; n < 4; ++n) {
                const int lcol = wn * 64 + n * 16 + fr;
                const float bv = bias[ntile * 256 + lcol];
#pragma unroll
                for (int j = 0; j < 4; ++j) {
                    const int lrow = wm * 128 + m * 16 + fq * 4 + j;
                    float v = acc[m][n][j] + bv;
                    float z2 = -2.3021582f * (v + 0.044715f * v * v * v);
                    float g = v / (1.0f + exp2f(z2));
                    lt[lrow * 256 + (lcol ^ ((lrow & 7) << 3))] = f2b(g);
                }
            }
        asm volatile("s_waitcnt lgkmcnt(0)" ::: "memory");
        BAR();
        u16* hidp = (u16*)outp;
        const long gbase = (long)(mtile * 256) * H_ + ntile * 256;
#pragma unroll
        for (int it = 0; it < 16; ++it) {
            const unsigned off = (unsigned)it * 8192u + (unsigned)tid * 16u;
            const int lrow = off >> 9;
            const unsigned lcolb = off & 511u;
            short8 vv = *(const short8*)(smem + (unsigned)(lrow << 9) + (lcolb ^ ((unsigned)(lrow & 7) << 4)));
            *(short8*)((char*)hidp + (gbase + (long)lrow * H_) * 2 + lcolb) = vv;
        }
    } else {
        float* op = (float*)outp;
        const int ncnt = *cnt;
        const int orow0 = mtile * 256 + wm * 128;
        const int ocol0 = ntile * 256 + wn * 64;
#pragma unroll
        for (int m = 0; m < 8; ++m)
#pragma unroll
            for (int j = 0; j < 4; ++j) {
                const int row = orow0 + m * 16 + fq * 4 + j;
                if (row < ncnt) {
                    const long ob = (long)idx[row] * D_;
#pragma unroll
                    for (int n = 0; n < 4; ++n) {
                        const int col = ocol0 + n * 16 + fr;
                        op[ob + col] = acc[m][n][j] + bias[col];
                    }
                }
            }
    }
#undef PHASE
#undef STAGE_A
#undef STAGE_B
#undef BAR
#undef VM4
}

// ---------- launcher ----------
extern "C" void kernel_launch(void* const* d_in, const int* in_sizes, int n_in,
                              void* d_out, int out_size, void* d_ws, size_t ws_size,
                              hipStream_t stream) {
    const float* x   = (const float*)d_in[0];
    const float* w_r = (const float*)d_in[1];
    const float* b_r = (const float*)d_in[2];
    const float* W1  = (const float*)d_in[3];
    const float* b1  = (const float*)d_in[4];
    const float* W2  = (const float*)d_in[5];
    const float* b2  = (const float*)d_in[6];
    float* out = (float*)d_out;

    char* p = (char*)d_ws;
    auto alloc = [&](size_t bytes) {
        char* q = p;
        p += (bytes + 255) & ~(size_t)255;
        return q;
    };
    float* wts = (float*)alloc((size_t)NTOK * 4);
    float* thr = (float*)alloc(B_ * 4);
    int*   cnt = (int*)alloc(4);
    int*   idx = (int*)alloc((size_t)MPAD * 4);
    u16*   xb  = (u16*)alloc((size_t)NTOK * D_ * 2);
    u16*   w1t = (u16*)alloc((size_t)H_ * D_ * 2);
    u16*   w2t = (u16*)alloc((size_t)H_ * D_ * 2);
    u16*   hid = (u16*)alloc((size_t)MPAD * H_ * 2);

    auto k1 = gemm8p<16, 16, 0>;
    auto k2 = gemm8p<64, 4, 1>;
    (void)hipFuncSetAttribute((const void*)k1, hipFuncAttributeMaxDynamicSharedMemorySize, 131072);
    (void)hipFuncSetAttribute((const void*)k2, hipFuncAttributeMaxDynamicSharedMemorySize, 131072);

    init_kernel<<<MPAD / 256, 256, 0, stream>>>(idx, cnt);
    router_kernel<<<NTOK / 4, 256, 0, stream>>>(x, w_r, b_r, out, xb, wts);
    select_kernel<<<B_, 256, 0, stream>>>(wts, thr);
    compact_kernel<<<NTOK / 256, 256, 0, stream>>>(wts, thr, idx, cnt);
    transpose_kernel<<<dim3(H_ / 32, D_ / 32), 256, 0, stream>>>(W1, w1t, D_, H_);
    transpose_kernel<<<dim3(D_ / 32, H_ / 32), 256, 0, stream>>>(W2, w2t, H_, D_);
    k1<<<dim3(16, 64), 512, 131072, stream>>>(xb, w1t, b1, idx, nullptr, hid);
    k2<<<dim3(4, 64), 512, 131072, stream>>>(hid, w2t, b2, idx, cnt, out);
}